// Round 2
// baseline (644.016 us; speedup 1.0000x reference)
//
#include <hip/hip_runtime.h>

// Problem constants (from reference)
#define Fn 8
#define Bn 4
#define Kn 2

constexpr unsigned HW   = 720u * 1280u;                 // 921600
constexpr unsigned CHW  = 3u * HW;                      // 2764800
constexpr unsigned OUT0 = Bn * 12u * HW;                // 44,236,800  (ce_blur_img_noisy)
constexpr unsigned OUT1 = (unsigned)Bn * Fn * CHW * Kn; // 176,947,200 (ce_code_up_ broadcast)
// out2 (ce_blur_img) follows at OUT0 + OUT1

typedef float f4 __attribute__((ext_vector_type(4)));

__device__ __forceinline__ f4 ntload(const float* p) {
    return __builtin_nontemporal_load(reinterpret_cast<const f4*>(p));
}
__device__ __forceinline__ void ntstore(float* p, f4 v) {
    __builtin_nontemporal_store(v, reinterpret_cast<f4*>(p));
}
__device__ __forceinline__ float stepf(float x) { return x > 0.0f ? 1.0f : 0.0f; }

__global__ __launch_bounds__(256) void cep_enc_kernel(const float* __restrict__ frames,
                                                      const float* __restrict__ cw,
                                                      float* __restrict__ out) {
    const unsigned q   = blockIdx.x * 256u + threadIdx.x;  // quad index over (c,h,w)
    const unsigned chw = q * 4u;
    if (chw >= CHW) return;
    const unsigned c  = chw / HW;
    const unsigned hw = chw - c * HW;

    // ---- 1. load ce_weight for all frames (read exactly once), step -> codes ----
    // 8 consecutive floats at cw[f*CHW*2 + chw*2] = [p0k0,p0k1,p1k0,p1k1,p2k0,p2k1,p3k0,p3k1]
    f4 ci[Fn][2];
#pragma unroll
    for (int f = 0; f < Fn; ++f) {
        const float* p = cw + (unsigned)f * (CHW * Kn) + chw * Kn;
        f4 a = ntload(p);
        f4 b = ntload(p + 4);
        f4 sa, sb;
        sa.x = stepf(a.x); sa.y = stepf(a.y); sa.z = stepf(a.z); sa.w = stepf(a.w);
        sb.x = stepf(b.x); sb.y = stepf(b.y); sb.z = stepf(b.z); sb.w = stepf(b.w);
        ci[f][0] = sa;
        ci[f][1] = sb;
    }

    float* out0 = out;                 // ce_blur_img_noisy (noise <= 1e-8, negligible)
    float* out1 = out + OUT0;          // ce_code_up_
    float* out2 = out + OUT0 + OUT1;   // ce_blur_img

    // ---- 2. broadcast code to out1 for all b (streaming, non-temporal) ----
#pragma unroll
    for (int b = 0; b < Bn; ++b) {
#pragma unroll
        for (int f = 0; f < Fn; ++f) {
            float* p = out1 + (unsigned)(b * Fn + f) * (CHW * Kn) + chw * Kn;
            ntstore(p,     ci[f][0]);
            ntstore(p + 4, ci[f][1]);
        }
    }

    // ---- 3. weighted / total / comp per batch ----
    const float inv = 1.0f / (float)Fn;
#pragma unroll
    for (int b = 0; b < Bn; ++b) {
        float sx = 0.f, sy = 0.f, sz = 0.f, sw = 0.f;   // sum over f
        float ax = 0.f, ay = 0.f, az = 0.f, aw = 0.f;   // weighted k=0
        float bx = 0.f, by = 0.f, bz = 0.f, bw = 0.f;   // weighted k=1
#pragma unroll
        for (int f = 0; f < Fn; ++f) {
            f4 fr = ntload(frames + (unsigned)(b * Fn + f) * CHW + chw);
            sx += fr.x; sy += fr.y; sz += fr.z; sw += fr.w;
            // k0 codes for pixels 0..3: ci[f][0].x, ci[f][0].z, ci[f][1].x, ci[f][1].z
            ax += fr.x * ci[f][0].x;  ay += fr.y * ci[f][0].z;
            az += fr.z * ci[f][1].x;  aw += fr.w * ci[f][1].z;
            // k1 codes: ci[f][0].y, ci[f][0].w, ci[f][1].y, ci[f][1].w
            bx += fr.x * ci[f][0].y;  by += fr.y * ci[f][0].w;
            bz += fr.z * ci[f][1].y;  bw += fr.w * ci[f][1].w;
        }
        sx *= inv; sy *= inv; sz *= inv; sw *= inv;
        ax *= inv; ay *= inv; az *= inv; aw *= inv;
        bx *= inv; by *= inv; bz *= inv; bw *= inv;

        f4 wk0 = {ax, ay, az, aw};
        f4 wk1 = {bx, by, bz, bw};
        f4 ck0 = {sx - ax, sy - ay, sz - az, sw - aw};
        f4 ck1 = {sx - bx, sy - by, sz - bz, sw - bw};

        // channel layout: ch = k*6 + s*3 + c  (s=0 weighted, s=1 comp)
        const unsigned base = (unsigned)b * 12u * HW + hw;
        ntstore(out0 + base + (0u + c) * HW, wk0);
        ntstore(out0 + base + (3u + c) * HW, ck0);
        ntstore(out0 + base + (6u + c) * HW, wk1);
        ntstore(out0 + base + (9u + c) * HW, ck1);

        ntstore(out2 + base + (0u + c) * HW, wk0);
        ntstore(out2 + base + (3u + c) * HW, ck0);
        ntstore(out2 + base + (6u + c) * HW, wk1);
        ntstore(out2 + base + (9u + c) * HW, ck1);
    }
}

extern "C" void kernel_launch(void* const* d_in, const int* in_sizes, int n_in,
                              void* d_out, int out_size, void* d_ws, size_t ws_size,
                              hipStream_t stream) {
    const float* frames = (const float*)d_in[0];
    const float* cw     = (const float*)d_in[1];
    float* out          = (float*)d_out;

    constexpr unsigned quads = CHW / 4u;   // 691200
    constexpr unsigned block = 256u;
    constexpr unsigned grid  = (quads + block - 1u) / block;  // 2700
    cep_enc_kernel<<<grid, block, 0, stream>>>(frames, cw, out);
}

// Round 3
// 379.374 us; speedup vs baseline: 1.6976x; 1.6976x over previous
//
#include <hip/hip_runtime.h>

// Problem constants (from reference)
#define Fn 8
#define Bn 4
#define Kn 2

constexpr unsigned HW   = 720u * 1280u;                 // 921600
constexpr unsigned CHW  = 3u * HW;                      // 2764800
constexpr unsigned OUT0 = Bn * 12u * HW;                // 44,236,800  (ce_blur_img_noisy)
constexpr unsigned OUT1 = (unsigned)Bn * Fn * CHW * Kn; // 176,947,200 (ce_code_up_ broadcast)
// out2 (ce_blur_img) follows at OUT0 + OUT1

typedef float f4 __attribute__((ext_vector_type(4)));

__device__ __forceinline__ float stepf(float x) { return x > 0.0f ? 1.0f : 0.0f; }

__global__ __launch_bounds__(256) void cep_enc_kernel(const float* __restrict__ frames,
                                                      const float* __restrict__ cw,
                                                      float* __restrict__ out) {
    const unsigned q   = blockIdx.x * 256u + threadIdx.x;  // quad index over (c,h,w)
    const unsigned chw = q * 4u;
    if (chw >= CHW) return;
    const unsigned c  = chw / HW;
    const unsigned hw = chw - c * HW;

    // ---- 1. issue ce_weight loads (16 x float4), step -> codes ----
    // 8 consecutive floats at cw[f*CHW*2 + chw*2] = [p0k0,p0k1,p1k0,p1k1,p2k0,p2k1,p3k0,p3k1]
    f4 ci[Fn][2];
#pragma unroll
    for (int f = 0; f < Fn; ++f) {
        const f4* p = reinterpret_cast<const f4*>(cw + (unsigned)f * (CHW * Kn) + chw * Kn);
        f4 a = p[0];
        f4 b = p[1];
        f4 sa, sb;
        sa.x = stepf(a.x); sa.y = stepf(a.y); sa.z = stepf(a.z); sa.w = stepf(a.w);
        sb.x = stepf(b.x); sb.y = stepf(b.y); sb.z = stepf(b.z); sb.w = stepf(b.w);
        ci[f][0] = sa;
        ci[f][1] = sb;
    }

    float* out0 = out;                 // ce_blur_img_noisy (noise <= 1e-8, negligible)
    float* out1 = out + OUT0;          // ce_code_up_
    float* out2 = out + OUT0 + OUT1;   // ce_blur_img

    // ---- 2. prefetch b=0 frames BEFORE the store burst, so the first
    //          load-wait does not drain the broadcast stores (vmcnt in-order) ----
    f4 fr[Fn];
#pragma unroll
    for (int f = 0; f < Fn; ++f)
        fr[f] = *reinterpret_cast<const f4*>(frames + (unsigned)f * CHW + chw);

    // ---- 3. broadcast code to out1 for all b (stores sit BEHIND b0 loads) ----
#pragma unroll
    for (int b = 0; b < Bn; ++b) {
#pragma unroll
        for (int f = 0; f < Fn; ++f) {
            f4* p = reinterpret_cast<f4*>(out1 + (unsigned)(b * Fn + f) * (CHW * Kn) + chw * Kn);
            p[0] = ci[f][0];
            p[1] = ci[f][1];
        }
    }

    // ---- 4. pipelined blur loop: wait b's loads -> compute -> issue (b+1) loads
    //          -> store b.  Load-waits never sit behind stores younger than one
    //          full iteration. ----
    const float inv = 1.0f / (float)Fn;
#pragma unroll
    for (int b = 0; b < Bn; ++b) {
        float sx = 0.f, sy = 0.f, sz = 0.f, sw = 0.f;   // sum over f
        float ax = 0.f, ay = 0.f, az = 0.f, aw = 0.f;   // weighted k=0
        float bx = 0.f, by = 0.f, bz = 0.f, bw = 0.f;   // weighted k=1
        f4 cur[Fn];
#pragma unroll
        for (int f = 0; f < Fn; ++f) cur[f] = fr[f];    // consume this b's loads

        // issue next b's loads now (before this b's stores)
        if (b + 1 < Bn) {
#pragma unroll
            for (int f = 0; f < Fn; ++f)
                fr[f] = *reinterpret_cast<const f4*>(frames + (unsigned)((b + 1) * Fn + f) * CHW + chw);
        }

#pragma unroll
        for (int f = 0; f < Fn; ++f) {
            f4 v = cur[f];
            sx += v.x; sy += v.y; sz += v.z; sw += v.w;
            // k0 codes for pixels 0..3: ci[f][0].x, ci[f][0].z, ci[f][1].x, ci[f][1].z
            ax += v.x * ci[f][0].x;  ay += v.y * ci[f][0].z;
            az += v.z * ci[f][1].x;  aw += v.w * ci[f][1].z;
            // k1 codes: ci[f][0].y, ci[f][0].w, ci[f][1].y, ci[f][1].w
            bx += v.x * ci[f][0].y;  by += v.y * ci[f][0].w;
            bz += v.z * ci[f][1].y;  bw += v.w * ci[f][1].w;
        }
        sx *= inv; sy *= inv; sz *= inv; sw *= inv;
        ax *= inv; ay *= inv; az *= inv; aw *= inv;
        bx *= inv; by *= inv; bz *= inv; bw *= inv;

        f4 wk0 = {ax, ay, az, aw};
        f4 wk1 = {bx, by, bz, bw};
        f4 ck0 = {sx - ax, sy - ay, sz - az, sw - aw};
        f4 ck1 = {sx - bx, sy - by, sz - bz, sw - bw};

        // channel layout: ch = k*6 + s*3 + c  (s=0 weighted, s=1 comp)
        const unsigned base = (unsigned)b * 12u * HW + hw;
        *reinterpret_cast<f4*>(out0 + base + (0u + c) * HW) = wk0;
        *reinterpret_cast<f4*>(out0 + base + (3u + c) * HW) = ck0;
        *reinterpret_cast<f4*>(out0 + base + (6u + c) * HW) = wk1;
        *reinterpret_cast<f4*>(out0 + base + (9u + c) * HW) = ck1;

        *reinterpret_cast<f4*>(out2 + base + (0u + c) * HW) = wk0;
        *reinterpret_cast<f4*>(out2 + base + (3u + c) * HW) = ck0;
        *reinterpret_cast<f4*>(out2 + base + (6u + c) * HW) = wk1;
        *reinterpret_cast<f4*>(out2 + base + (9u + c) * HW) = ck1;
    }
}

extern "C" void kernel_launch(void* const* d_in, const int* in_sizes, int n_in,
                              void* d_out, int out_size, void* d_ws, size_t ws_size,
                              hipStream_t stream) {
    const float* frames = (const float*)d_in[0];
    const float* cw     = (const float*)d_in[1];
    float* out          = (float*)d_out;

    constexpr unsigned quads = CHW / 4u;   // 691200
    constexpr unsigned block = 256u;
    constexpr unsigned grid  = (quads + block - 1u) / block;  // 2700
    cep_enc_kernel<<<grid, block, 0, stream>>>(frames, cw, out);
}